// Round 2
// baseline (1670.567 us; speedup 1.0000x reference)
//
#include <hip/hip_runtime.h>
#include <type_traits>

// Problem constants
#define B_  8
#define S_  512
#define H_  1024
#define NH_ 16
#define D_  64
#define M_  4096                       // B_*S_
#define MH_ ((size_t)M_ * (size_t)H_)  // 4,194,304 elements per [B,S,H] tensor

// ---------- bf16 helpers (raw bits) ----------
__device__ __forceinline__ float bf2f(unsigned short u) {
    return __uint_as_float(((unsigned)u) << 16);
}
__device__ __forceinline__ float lo2f(unsigned u) { return __uint_as_float(u << 16); }
__device__ __forceinline__ float hi2f(unsigned u) { return __uint_as_float(u & 0xffff0000u); }
__device__ __forceinline__ unsigned short f2bf(float f) {  // round-to-nearest-even
    unsigned u = __float_as_uint(f);
    return (unsigned short)((u + 0x7fffu + ((u >> 16) & 1u)) >> 16);
}
__device__ __forceinline__ float rdlane(float v, int lane) {
    return __int_as_float(__builtin_amdgcn_readlane(__float_as_int(v), lane));
}

// ---------------------------------------------------------------------------------
// GEMM: C[m,n] = sum_k A[m,k] * W[n,k] + bias[n]   (M=4096, N=K=1024)
// fp32 inputs, fp32 accumulate; OutT = unsigned short (bf16 ws) or float (d_out).
// 128x128 tile, BK=16, 256 threads, 8x8 micro-tile. blockIdx.z picks projection.
// ---------------------------------------------------------------------------------
struct GemmPtrs { const float* x; const float* w; const float* bias; void* o; };
struct GemmArgs { GemmPtrs p[7]; };

template <typename OutT>
__global__ __launch_bounds__(256) void gemm_bias_kernel(GemmArgs args) {
    const GemmPtrs gp = args.p[blockIdx.z];
    const int N = 1024, K = 1024;

    __shared__ __align__(16) float As[16][132];   // [k][m]
    __shared__ __align__(16) float Bs[16][132];   // [k][n]

    const int tid = threadIdx.x;
    const int tx  = tid & 15, ty = tid >> 4;
    const int row0 = blockIdx.y * 128;
    const int col0 = blockIdx.x * 128;
    const int lr = tid >> 1;            // 0..127 tile row/col for loading
    const int lk = (tid & 1) * 8;       // 0 or 8

    const float* aP = gp.x + (size_t)(row0 + lr) * K + lk;
    const float* wP = gp.w + (size_t)(col0 + lr) * K + lk;

    float acc[8][8];
#pragma unroll
    for (int i = 0; i < 8; ++i)
#pragma unroll
        for (int j = 0; j < 8; ++j) acc[i][j] = 0.f;

    for (int k0 = 0; k0 < K; k0 += 16) {
        float4 a0 = *(const float4*)(aP + k0);
        float4 a1 = *(const float4*)(aP + k0 + 4);
        float4 w0 = *(const float4*)(wP + k0);
        float4 w1 = *(const float4*)(wP + k0 + 4);

        As[lk + 0][lr] = a0.x; As[lk + 1][lr] = a0.y;
        As[lk + 2][lr] = a0.z; As[lk + 3][lr] = a0.w;
        As[lk + 4][lr] = a1.x; As[lk + 5][lr] = a1.y;
        As[lk + 6][lr] = a1.z; As[lk + 7][lr] = a1.w;
        Bs[lk + 0][lr] = w0.x; Bs[lk + 1][lr] = w0.y;
        Bs[lk + 2][lr] = w0.z; Bs[lk + 3][lr] = w0.w;
        Bs[lk + 4][lr] = w1.x; Bs[lk + 5][lr] = w1.y;
        Bs[lk + 6][lr] = w1.z; Bs[lk + 7][lr] = w1.w;
        __syncthreads();

#pragma unroll
        for (int kk = 0; kk < 16; ++kk) {
            float a[8], bb[8];
            *(float4*)&a[0]  = *(const float4*)&As[kk][ty * 8];
            *(float4*)&a[4]  = *(const float4*)&As[kk][ty * 8 + 4];
            *(float4*)&bb[0] = *(const float4*)&Bs[kk][tx * 8];
            *(float4*)&bb[4] = *(const float4*)&Bs[kk][tx * 8 + 4];
#pragma unroll
            for (int i = 0; i < 8; ++i)
#pragma unroll
                for (int j = 0; j < 8; ++j)
                    acc[i][j] = fmaf(a[i], bb[j], acc[i][j]);
        }
        __syncthreads();
    }

    OutT* o = (OutT*)gp.o;
#pragma unroll
    for (int i = 0; i < 8; ++i) {
        int r = row0 + ty * 8 + i;
        if constexpr (std::is_same<OutT, unsigned short>::value) {
            union { uint4 v; unsigned short h[8]; } pk;
#pragma unroll
            for (int j = 0; j < 8; ++j)
                pk.h[j] = f2bf(acc[i][j] + gp.bias[col0 + tx * 8 + j]);
            *(uint4*)(o + (size_t)r * N + col0 + tx * 8) = pk.v;
        } else {
            float4 v0, v1;
            v0.x = acc[i][0] + gp.bias[col0 + tx * 8 + 0];
            v0.y = acc[i][1] + gp.bias[col0 + tx * 8 + 1];
            v0.z = acc[i][2] + gp.bias[col0 + tx * 8 + 2];
            v0.w = acc[i][3] + gp.bias[col0 + tx * 8 + 3];
            v1.x = acc[i][4] + gp.bias[col0 + tx * 8 + 4];
            v1.y = acc[i][5] + gp.bias[col0 + tx * 8 + 5];
            v1.z = acc[i][6] + gp.bias[col0 + tx * 8 + 6];
            v1.w = acc[i][7] + gp.bias[col0 + tx * 8 + 7];
            *(float4*)((float*)o + (size_t)r * N + col0 + tx * 8)     = v0;
            *(float4*)((float*)o + (size_t)r * N + col0 + tx * 8 + 4) = v1;
        }
    }
}

// ---------------------------------------------------------------------------------
// Fused attention: content scores -> d_out map (fp32), online softmax, ctx -> ws fp32
// Block: 256 threads = 4 waves; wave handles 2 q-rows; block = 8 rows of one head.
// ---------------------------------------------------------------------------------
__global__ __launch_bounds__(256) void attn_kernel(
        const unsigned short* __restrict__ ws,
        const float* __restrict__ mask,
        float* __restrict__ amap,
        float* __restrict__ ctxo) {
    const unsigned short* q  = ws;
    const unsigned short* k  = ws + 1 * MH_;
    const unsigned short* v  = ws + 2 * MH_;
    const unsigned short* qp = ws + 3 * MH_;
    const unsigned short* kp = ws + 4 * MH_;
    const unsigned short* qf = ws + 5 * MH_;
    const unsigned short* kf = ws + 6 * MH_;

    __shared__ unsigned short kL[3][64][70];   // bf16, pad 70

    const int blk    = blockIdx.x;
    const int rowblk = blk & 63;     // S/8 = 64 row-blocks
    const int bh     = blk >> 6;     // 0..127
    const int b      = bh >> 4, h = bh & 15;
    const int row0   = rowblk * 8;
    const int tid    = threadIdx.x;
    const int wave   = tid >> 6, lane = tid & 63;
    const int r0g    = row0 + wave * 2;

    float qreg[6];
    {
        const unsigned short* qmaps[3] = { q, qp, qf };
#pragma unroll
        for (int m = 0; m < 3; ++m)
#pragma unroll
            for (int rp = 0; rp < 2; ++rp)
                qreg[m * 2 + rp] =
                    bf2f(qmaps[m][(size_t)(b * S_ + r0g + rp) * H_ + h * D_ + lane]);
    }

    float mrun[2] = { -1e30f, -1e30f };
    float lrun[2] = { 0.f, 0.f };
    float cacc[2] = { 0.f, 0.f };

    for (int t = 0; t < 8; ++t) {
        const int key0 = t * 64;
        __syncthreads();
        for (int idx = tid; idx < 1536; idx += 256) {
            int m   = idx >> 9;
            int rem = idx & 511;
            int key = rem >> 3;
            int dg  = rem & 7;
            const unsigned short* kmap = (m == 0) ? k : (m == 1) ? kp : kf;
            uint4 kv4 = *(const uint4*)(kmap + (size_t)(b * S_ + key0 + key) * H_ +
                                        h * D_ + dg * 8);
            unsigned* dst = (unsigned*)&kL[m][key][dg * 8];
            dst[0] = kv4.x; dst[1] = kv4.y; dst[2] = kv4.z; dst[3] = kv4.w;
        }
        __syncthreads();

        float s[2][3];
#pragma unroll
        for (int rp = 0; rp < 2; ++rp)
#pragma unroll
            for (int m = 0; m < 3; ++m) s[rp][m] = 0.f;

#pragma unroll
        for (int d2 = 0; d2 < 32; ++d2) {
            unsigned kc = *(const unsigned*)&kL[0][lane][d2 * 2];
            unsigned ku = *(const unsigned*)&kL[1][lane][d2 * 2];
            unsigned kw = *(const unsigned*)&kL[2][lane][d2 * 2];
            float kc0 = lo2f(kc), kc1 = hi2f(kc);
            float kp0 = lo2f(ku), kp1 = hi2f(ku);
            float kf0 = lo2f(kw), kf1 = hi2f(kw);
            const int d0 = d2 * 2, d1 = d2 * 2 + 1;
#pragma unroll
            for (int rp = 0; rp < 2; ++rp) {
                s[rp][0] = fmaf(rdlane(qreg[0 + rp], d0), kc0, s[rp][0]);
                s[rp][0] = fmaf(rdlane(qreg[0 + rp], d1), kc1, s[rp][0]);
                s[rp][1] = fmaf(rdlane(qreg[2 + rp], d0), kp0, s[rp][1]);
                s[rp][1] = fmaf(rdlane(qreg[2 + rp], d1), kp1, s[rp][1]);
                s[rp][2] = fmaf(rdlane(qreg[4 + rp], d0), kf0, s[rp][2]);
                s[rp][2] = fmaf(rdlane(qreg[4 + rp], d1), kf1, s[rp][2]);
            }
        }

        // content score map (output 1), raw q.k, fp32
        {
            size_t arow = ((size_t)bh * S_ + r0g) * S_;
            amap[arow + key0 + lane]      = s[0][0];
            amap[arow + S_ + key0 + lane] = s[1][0];
        }

        // online softmax update
        float e_keep[2];
#pragma unroll
        for (int rp = 0; rp < 2; ++rp) {
            float mval = mask[(size_t)b * S_ * S_ + (size_t)(r0g + rp) * S_ +
                              key0 + lane];
            float cm = (s[rp][0] + s[rp][1] + s[rp][2]) * 0.125f + mval;
            float tmax = cm;
#pragma unroll
            for (int off = 32; off >= 1; off >>= 1)
                tmax = fmaxf(tmax, __shfl_xor(tmax, off));
            float mnew = fmaxf(mrun[rp], tmax);
            float e = __expf(cm - mnew);
            float esum = e;
#pragma unroll
            for (int off = 32; off >= 1; off >>= 1)
                esum += __shfl_xor(esum, off);
            float alpha = __expf(mrun[rp] - mnew);
            lrun[rp] = lrun[rp] * alpha + esum;
            mrun[rp] = mnew;
            cacc[rp] *= alpha;
            e_keep[rp] = e;
        }

        // ctx accumulate: lane = d
        const unsigned short* vbase = v + (size_t)(b * S_ + key0) * H_ + h * D_ + lane;
#pragma unroll
        for (int j = 0; j < 64; ++j) {
            float e0 = rdlane(e_keep[0], j);
            float e1 = rdlane(e_keep[1], j);
            float vv = bf2f(vbase[(size_t)j * H_]);
            cacc[0] = fmaf(e0, vv, cacc[0]);
            cacc[1] = fmaf(e1, vv, cacc[1]);
        }
    }

#pragma unroll
    for (int rp = 0; rp < 2; ++rp) {
        float inv = 1.0f / lrun[rp];
        ctxo[(size_t)(b * S_ + r0g + rp) * H_ + h * D_ + lane] = cacc[rp] * inv;
    }
}

// ---------------------------------------------------------------------------------
extern "C" void kernel_launch(void* const* d_in, const int* in_sizes, int n_in,
                              void* d_out, int out_size, void* d_ws, size_t ws_size,
                              hipStream_t stream) {
    // Inputs (all fp32): 0 query, 1 key, 2 value, 3 mask, 4 pos_emb, 5 feat_emb,
    // then (W,b) pairs for q,k,v,qp,kp,qf,kf,d at indices 6..21.
    const float* in[22];
    for (int i = 0; i < 22; ++i) in[i] = (const float*)d_in[i];

    // ws layout: 7 bf16 projections (q,k,v,qp,kp,qf,kf), then fp32 ctx
    unsigned short* wsb = (unsigned short*)d_ws;                // 7*MH_ bf16 = 56 MB
    float*          ctx = (float*)((char*)d_ws + 7 * MH_ * 2);  // MH_ fp32 = 16 MB
    float*          out = (float*)d_out;

    GemmArgs ga;
    ga.p[0] = { in[0], in[6],  in[7],  wsb + 0 * MH_ };  // q
    ga.p[1] = { in[1], in[8],  in[9],  wsb + 1 * MH_ };  // k
    ga.p[2] = { in[2], in[10], in[11], wsb + 2 * MH_ };  // v
    ga.p[3] = { in[4], in[12], in[13], wsb + 3 * MH_ };  // qp
    ga.p[4] = { in[4], in[14], in[15], wsb + 4 * MH_ };  // kp
    ga.p[5] = { in[5], in[16], in[17], wsb + 5 * MH_ };  // qf
    ga.p[6] = { in[5], in[18], in[19], wsb + 6 * MH_ };  // kf
    gemm_bias_kernel<unsigned short><<<dim3(8, 32, 7), 256, 0, stream>>>(ga);

    // attention: content map -> out + MH_ (fp32), ctx -> ws fp32 region
    attn_kernel<<<dim3(B_ * NH_ * (S_ / 8)), 256, 0, stream>>>(
        wsb, in[3], out + MH_, ctx);

    // output projection: hidden = ctx @ Wd^T + bd -> out[0 : MH_)
    GemmArgs gf;
    gf.p[0] = { ctx, in[20], in[21], out };
    for (int i = 1; i < 7; ++i) gf.p[i] = gf.p[0];
    gemm_bias_kernel<float><<<dim3(8, 32, 1), 256, 0, stream>>>(gf);
}

// Round 3
// 1043.455 us; speedup vs baseline: 1.6010x; 1.6010x over previous
//
#include <hip/hip_runtime.h>

// Problem constants
#define B_  8
#define S_  512
#define H_  1024
#define NH_ 16
#define D_  64
#define M_  4096                       // B_*S_
#define HH_ ((size_t)H_ * H_)          // 1,048,576  (one weight matrix)
#define MH_ ((size_t)M_ * H_)          // 4,194,304  (one [B,S,H] tensor)

typedef __attribute__((ext_vector_type(8))) short short8;
typedef __attribute__((ext_vector_type(4))) float f32x4;

// ---------- bf16 helpers (raw bits) ----------
__device__ __forceinline__ float bf2f(unsigned short u) {
    return __uint_as_float(((unsigned)u) << 16);
}
__device__ __forceinline__ float lo2f(unsigned u) { return __uint_as_float(u << 16); }
__device__ __forceinline__ float hi2f(unsigned u) { return __uint_as_float(u & 0xffff0000u); }
__device__ __forceinline__ unsigned short f2bf(float f) {  // round-to-nearest-even
    unsigned u = __float_as_uint(f);
    return (unsigned short)((u + 0x7fffu + ((u >> 16) & 1u)) >> 16);
}
__device__ __forceinline__ float rdlane(float v, int lane) {
    return __int_as_float(__builtin_amdgcn_readlane(__float_as_int(v), lane));
}
__device__ __forceinline__ void gload_lds16(const void* g, void* l) {
    __builtin_amdgcn_global_load_lds(
        (const __attribute__((address_space(1))) void*)g,
        (__attribute__((address_space(3))) void*)l, 16, 0, 0);
}

// ---------------------------------------------------------------------------------
// Weight conversion: 8 matrices [1024x1024] fp32 -> bf16.  grid (1024, 8) x 256.
// ---------------------------------------------------------------------------------
struct CvtArgs { const float* src[8]; unsigned short* dst[8]; };

__global__ __launch_bounds__(256) void cvt_kernel(CvtArgs a) {
    const int seg = blockIdx.y;
    const float* s = a.src[seg];
    unsigned short* d = a.dst[seg];
    const size_t i = ((size_t)blockIdx.x * 256 + threadIdx.x) * 4;
    float4 f = *(const float4*)(s + i);
    union { unsigned long long v; unsigned short h[4]; } pk;
    pk.h[0] = f2bf(f.x); pk.h[1] = f2bf(f.y);
    pk.h[2] = f2bf(f.z); pk.h[3] = f2bf(f.w);
    *(unsigned long long*)(d + i) = pk.v;
}

// ---------------------------------------------------------------------------------
// MFMA GEMM: C[m,n] = sum_k A[m,k]*W[n,k] + bias[n]   (M=4096, N=K=1024)
// 128x128 tile, BK=32, 256 thr = 4 waves, each wave 64x64 via 4x4 blocks of
// v_mfma_f32_16x16x32_bf16. B (and A when bf16) staged with global_load_lds
// width=16.  LDS granule XOR-swizzle: source k-granule q of row r sits at slot
// q ^ ((r>>1)&3)  -> conflict-free ds_read_b128 frag reads AND ds_write stages.
// A_FP32: A is fp32 in global, converted during staging (manual ds_write path).
// ---------------------------------------------------------------------------------
struct GemmPtrs { const void* x; const unsigned short* w; const float* bias; void* o; };
struct GemmArgs { GemmPtrs p[7]; };

template <bool A_FP32, bool OUT_BF16>
__global__ __launch_bounds__(256) void mfma_gemm(GemmArgs args) {
    const GemmPtrs gp = args.p[blockIdx.z];
    __shared__ unsigned short As[128 * 32];
    __shared__ unsigned short Bs[128 * 32];

    const int tid  = threadIdx.x;
    const int wave = tid >> 6, lane = tid & 63;
    const int row0 = blockIdx.y * 128, col0 = blockIdx.x * 128;
    const int wr = (wave & 1) * 64, wc = (wave >> 1) * 64;
    const int lr = lane & 15;

    // staging granules p = tid and tid+256:  row = p>>2, slot = p&3,
    // source k-granule q = slot ^ ((row>>1)&3)
    const int br1 = tid >> 2,      bq1 = (tid & 3) ^ ((br1 >> 1) & 3);
    const int p2  = tid + 256;
    const int br2 = p2 >> 2,       bq2 = (p2 & 3) ^ ((br2 >> 1) & 3);

    const unsigned short* wp1 = gp.w + (size_t)(col0 + br1) * H_ + bq1 * 8;
    const unsigned short* wp2 = gp.w + (size_t)(col0 + br2) * H_ + bq2 * 8;
    unsigned short* bd1 = Bs + tid * 8;
    unsigned short* bd2 = Bs + (tid + 256) * 8;

    // A bf16 path (global_load_lds)
    const unsigned short* ap1 =
        (const unsigned short*)gp.x + (size_t)(row0 + br1) * H_ + bq1 * 8;
    const unsigned short* ap2 =
        (const unsigned short*)gp.x + (size_t)(row0 + br2) * H_ + bq2 * 8;
    unsigned short* ad1 = As + tid * 8;
    unsigned short* ad2 = As + (tid + 256) * 8;

    // A fp32 path (load + cvt + ds_write): thread t -> row t>>1, k-half t&1
    const int ar = tid >> 1, ah = tid & 1, asw = (ar >> 1) & 3;
    const int g0 = (ah * 2) ^ asw, g1 = (ah * 2 + 1) ^ asw;
    const float* ax = (const float*)gp.x + (size_t)(row0 + ar) * H_ + ah * 16;

    // fragment-read granule slot (same formula for As and Bs; independent of mi/ni)
    const int slot8 = (((lane >> 4) ^ ((lr >> 1) & 3)) << 3);

    f32x4 acc[4][4];
#pragma unroll
    for (int mi = 0; mi < 4; ++mi)
#pragma unroll
        for (int ni = 0; ni < 4; ++ni) acc[mi][ni] = (f32x4)0.f;

    for (int k0 = 0; k0 < H_; k0 += 32) {
        __syncthreads();
        if (A_FP32) {
            float4 f0 = *(const float4*)(ax + k0);
            float4 f1 = *(const float4*)(ax + k0 + 4);
            float4 f2 = *(const float4*)(ax + k0 + 8);
            float4 f3 = *(const float4*)(ax + k0 + 12);
            union { short8 v; unsigned short h[8]; } u0, u1;
            u0.h[0] = f2bf(f0.x); u0.h[1] = f2bf(f0.y);
            u0.h[2] = f2bf(f0.z); u0.h[3] = f2bf(f0.w);
            u0.h[4] = f2bf(f1.x); u0.h[5] = f2bf(f1.y);
            u0.h[6] = f2bf(f1.z); u0.h[7] = f2bf(f1.w);
            u1.h[0] = f2bf(f2.x); u1.h[1] = f2bf(f2.y);
            u1.h[2] = f2bf(f2.z); u1.h[3] = f2bf(f2.w);
            u1.h[4] = f2bf(f3.x); u1.h[5] = f2bf(f3.y);
            u1.h[6] = f2bf(f3.z); u1.h[7] = f2bf(f3.w);
            *(short8*)(As + ar * 32 + g0 * 8) = u0.v;
            *(short8*)(As + ar * 32 + g1 * 8) = u1.v;
        } else {
            gload_lds16(ap1 + k0, ad1);
            gload_lds16(ap2 + k0, ad2);
        }
        gload_lds16(wp1 + k0, bd1);
        gload_lds16(wp2 + k0, bd2);
        __syncthreads();

        short8 af[4], bfr[4];
#pragma unroll
        for (int mi = 0; mi < 4; ++mi)
            af[mi] = *(const short8*)(As + (wr + mi * 16 + lr) * 32 + slot8);
#pragma unroll
        for (int ni = 0; ni < 4; ++ni)
            bfr[ni] = *(const short8*)(Bs + (wc + ni * 16 + lr) * 32 + slot8);
#pragma unroll
        for (int mi = 0; mi < 4; ++mi)
#pragma unroll
            for (int ni = 0; ni < 4; ++ni)
                acc[mi][ni] = __builtin_amdgcn_mfma_f32_16x16x32_bf16(
                    af[mi], bfr[ni], acc[mi][ni], 0, 0, 0);
    }

    // epilogue: C/D layout col = lane&15, row = (lane>>4)*4 + reg  [m89/m91]
    float bv[4];
#pragma unroll
    for (int ni = 0; ni < 4; ++ni)
        bv[ni] = gp.bias[col0 + wc + ni * 16 + lr];

#pragma unroll
    for (int mi = 0; mi < 4; ++mi)
#pragma unroll
        for (int r = 0; r < 4; ++r) {
            const int row = row0 + wr + mi * 16 + (lane >> 4) * 4 + r;
#pragma unroll
            for (int ni = 0; ni < 4; ++ni) {
                const int col = col0 + wc + ni * 16 + lr;
                const float v = acc[mi][ni][r] + bv[ni];
                if (OUT_BF16)
                    ((unsigned short*)gp.o)[(size_t)row * H_ + col] = f2bf(v);
                else
                    ((float*)gp.o)[(size_t)row * H_ + col] = v;
            }
        }
}

// ---------------------------------------------------------------------------------
// Fused attention (unchanged from round 2 except ctx out is bf16 for final GEMM).
// ---------------------------------------------------------------------------------
__global__ __launch_bounds__(256) void attn_kernel(
        const unsigned short* __restrict__ ws,
        const float* __restrict__ mask,
        float* __restrict__ amap,
        unsigned short* __restrict__ ctxo) {
    const unsigned short* q  = ws;
    const unsigned short* k  = ws + 1 * MH_;
    const unsigned short* v  = ws + 2 * MH_;
    const unsigned short* qp = ws + 3 * MH_;
    const unsigned short* kp = ws + 4 * MH_;
    const unsigned short* qf = ws + 5 * MH_;
    const unsigned short* kf = ws + 6 * MH_;

    __shared__ unsigned short kL[3][64][70];

    const int blk    = blockIdx.x;
    const int rowblk = blk & 63;
    const int bh     = blk >> 6;
    const int b      = bh >> 4, h = bh & 15;
    const int row0   = rowblk * 8;
    const int tid    = threadIdx.x;
    const int wave   = tid >> 6, lane = tid & 63;
    const int r0g    = row0 + wave * 2;

    float qreg[6];
    {
        const unsigned short* qmaps[3] = { q, qp, qf };
#pragma unroll
        for (int m = 0; m < 3; ++m)
#pragma unroll
            for (int rp = 0; rp < 2; ++rp)
                qreg[m * 2 + rp] =
                    bf2f(qmaps[m][(size_t)(b * S_ + r0g + rp) * H_ + h * D_ + lane]);
    }

    float mrun[2] = { -1e30f, -1e30f };
    float lrun[2] = { 0.f, 0.f };
    float cacc[2] = { 0.f, 0.f };

    for (int t = 0; t < 8; ++t) {
        const int key0 = t * 64;
        __syncthreads();
        for (int idx = tid; idx < 1536; idx += 256) {
            int m   = idx >> 9;
            int rem = idx & 511;
            int key = rem >> 3;
            int dg  = rem & 7;
            const unsigned short* kmap = (m == 0) ? k : (m == 1) ? kp : kf;
            uint4 kv4 = *(const uint4*)(kmap + (size_t)(b * S_ + key0 + key) * H_ +
                                        h * D_ + dg * 8);
            unsigned* dst = (unsigned*)&kL[m][key][dg * 8];
            dst[0] = kv4.x; dst[1] = kv4.y; dst[2] = kv4.z; dst[3] = kv4.w;
        }
        __syncthreads();

        float s[2][3];
#pragma unroll
        for (int rp = 0; rp < 2; ++rp)
#pragma unroll
            for (int m = 0; m < 3; ++m) s[rp][m] = 0.f;

#pragma unroll
        for (int d2 = 0; d2 < 32; ++d2) {
            unsigned kc = *(const unsigned*)&kL[0][lane][d2 * 2];
            unsigned ku = *(const unsigned*)&kL[1][lane][d2 * 2];
            unsigned kw = *(const unsigned*)&kL[2][lane][d2 * 2];
            float kc0 = lo2f(kc), kc1 = hi2f(kc);
            float kp0 = lo2f(ku), kp1 = hi2f(ku);
            float kf0 = lo2f(kw), kf1 = hi2f(kw);
            const int d0 = d2 * 2, d1 = d2 * 2 + 1;
#pragma unroll
            for (int rp = 0; rp < 2; ++rp) {
                s[rp][0] = fmaf(rdlane(qreg[0 + rp], d0), kc0, s[rp][0]);
                s[rp][0] = fmaf(rdlane(qreg[0 + rp], d1), kc1, s[rp][0]);
                s[rp][1] = fmaf(rdlane(qreg[2 + rp], d0), kp0, s[rp][1]);
                s[rp][1] = fmaf(rdlane(qreg[2 + rp], d1), kp1, s[rp][1]);
                s[rp][2] = fmaf(rdlane(qreg[4 + rp], d0), kf0, s[rp][2]);
                s[rp][2] = fmaf(rdlane(qreg[4 + rp], d1), kf1, s[rp][2]);
            }
        }

        {
            size_t arow = ((size_t)bh * S_ + r0g) * S_;
            amap[arow + key0 + lane]      = s[0][0];
            amap[arow + S_ + key0 + lane] = s[1][0];
        }

        float e_keep[2];
#pragma unroll
        for (int rp = 0; rp < 2; ++rp) {
            float mval = mask[(size_t)b * S_ * S_ + (size_t)(r0g + rp) * S_ +
                              key0 + lane];
            float cm = (s[rp][0] + s[rp][1] + s[rp][2]) * 0.125f + mval;
            float tmax = cm;
#pragma unroll
            for (int off = 32; off >= 1; off >>= 1)
                tmax = fmaxf(tmax, __shfl_xor(tmax, off));
            float mnew = fmaxf(mrun[rp], tmax);
            float e = __expf(cm - mnew);
            float esum = e;
#pragma unroll
            for (int off = 32; off >= 1; off >>= 1)
                esum += __shfl_xor(esum, off);
            float alpha = __expf(mrun[rp] - mnew);
            lrun[rp] = lrun[rp] * alpha + esum;
            mrun[rp] = mnew;
            cacc[rp] *= alpha;
            e_keep[rp] = e;
        }

        const unsigned short* vbase = v + (size_t)(b * S_ + key0) * H_ + h * D_ + lane;
#pragma unroll
        for (int j = 0; j < 64; ++j) {
            float e0 = rdlane(e_keep[0], j);
            float e1 = rdlane(e_keep[1], j);
            float vv = bf2f(vbase[(size_t)j * H_]);
            cacc[0] = fmaf(e0, vv, cacc[0]);
            cacc[1] = fmaf(e1, vv, cacc[1]);
        }
    }

#pragma unroll
    for (int rp = 0; rp < 2; ++rp) {
        float inv = 1.0f / lrun[rp];
        ctxo[(size_t)(b * S_ + r0g + rp) * H_ + h * D_ + lane] =
            f2bf(cacc[rp] * inv);
    }
}

// ---------------------------------------------------------------------------------
extern "C" void kernel_launch(void* const* d_in, const int* in_sizes, int n_in,
                              void* d_out, int out_size, void* d_ws, size_t ws_size,
                              hipStream_t stream) {
    // Inputs (fp32): 0 query, 1 key, 2 value, 3 mask, 4 pos_emb, 5 feat_emb,
    // then (W,b) pairs for q,k,v,qp,kp,qf,kf,d at 6..21.
    const float* in[22];
    for (int i = 0; i < 22; ++i) in[i] = (const float*)d_in[i];

    // ws layout: 8 bf16 weights (16 MB) | 7 bf16 projections (56 MB) | bf16 ctx (8 MB)
    unsigned short* wsW = (unsigned short*)d_ws;
    unsigned short* wsP = wsW + 8 * HH_;
    unsigned short* wsC = wsP + 7 * MH_;
    float*          out = (float*)d_out;

    // 1) weights fp32 -> bf16
    CvtArgs ca;
    {
        const int widx[8] = { 6, 8, 10, 12, 14, 16, 18, 20 };
        for (int i = 0; i < 8; ++i) { ca.src[i] = in[widx[i]]; ca.dst[i] = wsW + i * HH_; }
    }
    cvt_kernel<<<dim3(1024, 8), 256, 0, stream>>>(ca);

    // 2) 7 projections (A fp32, out bf16)
    GemmArgs ga;
    ga.p[0] = { in[0], wsW + 0 * HH_, in[7],  wsP + 0 * MH_ };  // q
    ga.p[1] = { in[1], wsW + 1 * HH_, in[9],  wsP + 1 * MH_ };  // k
    ga.p[2] = { in[2], wsW + 2 * HH_, in[11], wsP + 2 * MH_ };  // v
    ga.p[3] = { in[4], wsW + 3 * HH_, in[13], wsP + 3 * MH_ };  // qp
    ga.p[4] = { in[4], wsW + 4 * HH_, in[15], wsP + 4 * MH_ };  // kp
    ga.p[5] = { in[5], wsW + 5 * HH_, in[17], wsP + 5 * MH_ };  // qf
    ga.p[6] = { in[5], wsW + 6 * HH_, in[19], wsP + 6 * MH_ };  // kf
    mfma_gemm<true, true><<<dim3(8, 32, 7), 256, 0, stream>>>(ga);

    // 3) attention: content map -> out + MH_ (fp32), ctx -> wsC (bf16)
    attn_kernel<<<dim3(B_ * NH_ * (S_ / 8)), 256, 0, stream>>>(
        wsP, in[3], out + MH_, wsC);

    // 4) output projection (A bf16, out fp32)
    GemmArgs gf;
    gf.p[0] = { wsC, wsW + 7 * HH_, in[21], out };
    for (int i = 1; i < 7; ++i) gf.p[i] = gf.p[0];
    mfma_gemm<false, false><<<dim3(8, 32, 1), 256, 0, stream>>>(gf);
}